// Round 16
// baseline (147.630 us; speedup 1.0000x reference)
//
#include <hip/hip_runtime.h>
#include <hip/hip_bf16.h>

// MHSA: B=4, P=4096, C=256, H=4, D=64. fp32 in/out, bf16 MFMA internally.
#define DIMC 256
#define NHEADS 4
#define HDIM 64
#define BATCH 4
#define SEQ 4096
#define MTOT (BATCH*SEQ)   // 16384
#define SCALE_LOG2E 0.18033688011112042f  // 0.125 * log2(e); softmax done in exp2 domain

typedef __attribute__((ext_vector_type(8))) __bf16 bf16x8;
typedef __attribute__((ext_vector_type(4))) __bf16 bf16x4;
typedef __attribute__((ext_vector_type(2))) __bf16 bf16x2;
typedef __attribute__((ext_vector_type(4))) float f32x4;
typedef __attribute__((ext_vector_type(16))) float f32x16;
typedef __attribute__((ext_vector_type(2))) unsigned uint2v;
typedef __attribute__((ext_vector_type(4))) unsigned uint4v;

__device__ inline void gll16(const void* g, void* l) {
  // async global->LDS, 16B per lane. LDS dest must be wave-uniform base + lane*16.
  __builtin_amdgcn_global_load_lds((const __attribute__((address_space(1))) unsigned int*)g,
                                   (__attribute__((address_space(3))) unsigned int*)l, 16, 0, 0);
}

// Single v_exp_f32 via the compiler intrinsic (R5 lesson: never raw asm TRANS ops).
__device__ inline float vexp2(float x) { return __builtin_amdgcn_exp2f(x); }

// Pack two f32 -> one u32 of 2 bf16 (RNE). Plain casts (NOT inline asm).
__device__ inline unsigned pack2(float lo, float hi) {
  bf16x2 p; p[0] = (__bf16)lo; p[1] = (__bf16)hi;
  return __builtin_bit_cast(unsigned, p);
}

// Swizzled read from a 64-bf16-row (128B) LDS tile: chunk' = c16 ^ (row&7).
// (GEMM tiles; conflict-free for 16-row read groups — verified R1.)
__device__ inline bf16x8 swzread(const __bf16* base, int row, int c16) {
  return *reinterpret_cast<const bf16x8*>(
      reinterpret_cast<const char*>(base) + row * 128 + ((c16 ^ (row & 7)) << 4));
}

// R15: swizzled read from a 128-bf16-row (256B) LDS tile: chunk' = lc ^ (row&15).
// 16 XOR slots for 32 same-column lanes -> 2-way conflict = free (m136),
// vs 4-way on the 128B-row layout (R11's 8.4e6 conflict counts).
__device__ inline bf16x8 swzread2(const __bf16* base, int row, int lc) {
  return *reinterpret_cast<const bf16x8*>(
      reinterpret_cast<const char*>(base) + row * 256 + ((lc ^ (row & 15)) << 4));
}

// ---------------- prep kernels ----------------

__global__ __launch_bounds__(256) void cvt_x_kernel(const float* __restrict__ x, __bf16* __restrict__ xb) {
  int i = (blockIdx.x * 256 + threadIdx.x) * 4;
  float4 v = *reinterpret_cast<const float4*>(x + i);
  bf16x4 o;
  o[0] = (__bf16)v.x; o[1] = (__bf16)v.y; o[2] = (__bf16)v.z; o[3] = (__bf16)v.w;
  *reinterpret_cast<bf16x4*>(xb + i) = o;
}

// Builds Wqkv^T [768][256] (Wq scaled by 0.125*log2e), Wo^T [256][256], and
// (rows 1024..1026) the scaled/merged qkv bias.
__global__ __launch_bounds__(256) void prep_w(const float* __restrict__ Wq, const float* __restrict__ Wk,
                                              const float* __restrict__ Wv, const float* __restrict__ Wo,
                                              const float* __restrict__ bq, const float* __restrict__ bk,
                                              const float* __restrict__ bv,
                                              __bf16* __restrict__ wqkvt, __bf16* __restrict__ wot,
                                              float* __restrict__ biasq) {
  int row = blockIdx.x;        // 0..1026
  int k = threadIdx.x;         // 0..255
  if (row < 768) {
    const float* src; float scale = 1.f; int n = row & 255;
    if (row < 256)      { src = Wq; scale = SCALE_LOG2E; }
    else if (row < 512) { src = Wk; }
    else                { src = Wv; }
    wqkvt[row * 256 + k] = (__bf16)(src[k * 256 + n] * scale);
  } else if (row < 1024) {
    int n = row - 768;
    wot[n * 256 + k] = (__bf16)(Wo[k * 256 + n]);
  } else {
    int i = (row - 1024) * 256 + k;   // 0..767
    biasq[i] = (i < 256) ? bq[i] * SCALE_LOG2E : (i < 512 ? bk[i - 256] : bv[i - 512]);
  }
}

// ---------------- GEMM: C[m][n] = sum_k A[m][k]*Bt[n][k] + bias[n] ----------------
// 128x128 tile, BK=64, 4 waves (2x2 of 64x64), mfma 16x16x32 bf16. T2-swizzled LDS.
// Pure gll16 staging for BOTH operands (R12 lesson: fp32 reg-staging of A cost
// ~16 µs — async global_load_lds is worth more than fusing the cvt).
// MODE 0: scatter q/k into [bh][p][d] and V directly transposed into vt [bh][d][p].
// MODE 1: fp32 out [m][256].
template<int MODE>
__global__ __launch_bounds__(256) void gemm_bt(const __bf16* __restrict__ A, const __bf16* __restrict__ Bt,
                                               const float* __restrict__ bias,
                                               __bf16* __restrict__ q_ws, __bf16* __restrict__ k_ws,
                                               __bf16* __restrict__ vt_ws, float* __restrict__ fout) {
  __shared__ __align__(16) __bf16 As[128 * 64];
  __shared__ __align__(16) __bf16 Bs[128 * 64];
  const int tid = threadIdx.x;
  const int lane = tid & 63, wave = tid >> 6;
  const int wr = wave >> 1, wc = wave & 1;
  const int r16 = lane & 15, g4 = lane >> 4;
  const int m0 = blockIdx.y * 128, n0 = blockIdx.x * 128;
  f32x4 acc[4][4] = {};
  for (int k0 = 0; k0 < DIMC; k0 += 64) {
    #pragma unroll
    for (int it = 0; it < 4; ++it) {
      int e = it * 256 + tid;           // 16B chunk id
      int r = e >> 3, c = e & 7;
      int cs = c ^ (r & 7);             // pre-swizzled source column (rule #21)
      gll16(A  + (size_t)(m0 + r) * DIMC + k0 + cs * 8, As + e * 8);
      gll16(Bt + (size_t)(n0 + r) * DIMC + k0 + cs * 8, Bs + e * 8);
    }
    __syncthreads();
    #pragma unroll
    for (int kk = 0; kk < 2; ++kk) {
      bf16x8 af[4], bfr[4];
      #pragma unroll
      for (int mi = 0; mi < 4; ++mi)
        af[mi] = swzread(As, wr * 64 + mi * 16 + r16, kk * 4 + g4);
      #pragma unroll
      for (int ni = 0; ni < 4; ++ni)
        bfr[ni] = swzread(Bs, wc * 64 + ni * 16 + r16, kk * 4 + g4);
      #pragma unroll
      for (int mi = 0; mi < 4; ++mi)
        #pragma unroll
        for (int ni = 0; ni < 4; ++ni)
          acc[mi][ni] = __builtin_amdgcn_mfma_f32_16x16x32_bf16(af[mi], bfr[ni], acc[mi][ni], 0, 0, 0);
    }
    __syncthreads();
  }
  // Epilogue. C/D layout: col = lane&15, row = (lane>>4)*4 + reg.
  #pragma unroll
  for (int mi = 0; mi < 4; ++mi)
    #pragma unroll
    for (int ni = 0; ni < 4; ++ni)
      #pragma unroll
      for (int r = 0; r < 4; ++r) {
        int m = m0 + wr * 64 + mi * 16 + g4 * 4 + r;
        int n = n0 + wc * 64 + ni * 16 + r16;
        float v = acc[mi][ni][r] + bias[n];
        if (MODE == 0) {
          int b = m >> 12, p = m & 4095;
          int sect = n >> 8, nc = n & 255;
          int h = nc >> 6, d = nc & 63;
          __bf16 hv = (__bf16)v;
          size_t bhb = (size_t)(b * NHEADS + h);
          if (sect == 0)      q_ws[(bhb * SEQ + p) * HDIM + d] = hv;
          else if (sect == 1) k_ws[(bhb * SEQ + p) * HDIM + d] = hv;
          else                vt_ws[(bhb * HDIM + d) * SEQ + p] = hv;  // direct V^T
        } else {
          fout[(size_t)m * DIMC + n] = v;
        }
      }
}

// ---------------- flash attention (split-KV x2, NO atomics) ----------------
// R14 structure kept (32x32x16 core, dv[4] denominator chains, compile-time
// double-buffer unroll, bf16 partial-O plain stores + combine).
// R15: K/Vt LDS tiles re-laid as [32 rows][128 bf16] (256B rows): row r holds
// kv(or d) in {r, r+32}; logical chunk lc = (ni|di)*8 + ks*2 + h5; stored
// chunk = lc ^ (r&15). 32 same-column lanes now spread over 16 bank residues
// -> 2-way (free, m136) instead of 4-way; kills R11's 8.4e6 conflict counts.
//   S^T = K Q^T: D col=lane&31=q, row kv=(r&3)+8*(r>>2)+4*(lane>>5)+32*ni [m74/m101].
//   p32swap semantics (R7-validated): d0={a.lo32,b.lo32}, d1={a.hi32,b.hi32}.
__global__ __launch_bounds__(256, 4) void attn_kernel(const __bf16* __restrict__ q_ws, const __bf16* __restrict__ k_ws,
                                                      const __bf16* __restrict__ vt_ws,
                                                      __bf16* __restrict__ o_part, float* __restrict__ lsum_part) {
  __shared__ __align__(16) __bf16 Ks[2][32 * 128];   // [row][256B], swizzled (R15)
  __shared__ __align__(16) __bf16 Vts[2][32 * 128];  // [row][256B], swizzled (R15)
  const int tid = threadIdx.x;
  const int lane = tid & 63;
  const int l31 = lane & 31, h5 = lane >> 5;
  // XCD-bijective swizzle over 1024 blocks: 128 consecutive wgs (2 heads) per XCD.
  int bid = blockIdx.x;
  int wg = (bid & 7) * 128 + (bid >> 3);
  int bh = wg >> 6, rrw = wg & 63;
  int qb = rrw >> 1, half = rrw & 1;
  int b = bh >> 2, h = bh & 3;
  const __bf16* Qp  = q_ws  + (size_t)bh * SEQ * HDIM;
  const __bf16* Kp  = k_ws  + (size_t)bh * SEQ * HDIM;
  const __bf16* Vtp = vt_ws + (size_t)bh * HDIM * SEQ;
  const int q0 = qb * 128 + (tid >> 6) * 32;
  const int kvb = half * (SEQ / 2);
  // Q B-frag: col=lane&31=q, k = ks*16 + h5*8 + j
  bf16x8 qf[4];
  #pragma unroll
  for (int ks = 0; ks < 4; ++ks)
    qf[ks] = *reinterpret_cast<const bf16x8*>(Qp + (size_t)(q0 + l31) * HDIM + ks * 16 + h5 * 8);
  f32x16 o_acc[2] = {};
  f32x4 dv = {};                      // 4 independent denominator chains (R14)

  // R15 staging: 512 chunks/buffer, 16 chunks per 256B row. For stored chunk
  // e (r = e>>4, c = e&15): logical lc = c ^ (r&15); K-source row kv = r +
  // 32*(lc>>3), octet (lc&7)*8; V-source d = r + 32*(lc>>3), kv-octet (lc&7)*8.
  // Per-thread-constant bases; gll16 dest stays linear (rule #21).
  const int e0 = tid,       r0 = e0 >> 4, lc0 = (e0 & 15) ^ (r0 & 15);
  const int e1 = tid + 256, r1 = e1 >> 4, lc1 = (e1 & 15) ^ (r1 & 15);
  const __bf16* kS0 = Kp  + (size_t)(r0 + 32 * (lc0 >> 3)) * HDIM + (lc0 & 7) * 8;
  const __bf16* kS1 = Kp  + (size_t)(r1 + 32 * (lc1 >> 3)) * HDIM + (lc1 & 7) * 8;
  const __bf16* vS0 = Vtp + (size_t)(r0 + 32 * (lc0 >> 3)) * SEQ  + (lc0 & 7) * 8;
  const __bf16* vS1 = Vtp + (size_t)(r1 + 32 * (lc1 >> 3)) * SEQ  + (lc1 & 7) * 8;

  #define STAGE(buf, kv0) do { \
      gll16(kS0 + (size_t)(kv0) * HDIM, &Ks[buf][tid * 8]); \
      gll16(kS1 + (size_t)(kv0) * HDIM, &Ks[buf][(tid + 256) * 8]); \
      gll16(vS0 + (kv0),                &Vts[buf][tid * 8]); \
      gll16(vS1 + (kv0),                &Vts[buf][(tid + 256) * 8]); \
    } while (0)

  // One KV tile with COMPILE-TIME buffer index BUF; optionally stages
  // the opposite buffer for tile (kv0_next) before compute.
  #define TILE(BUF, DO_STAGE, kv0_next) do { \
    if (DO_STAGE) STAGE(BUF ^ 1, kv0_next); \
    f32x16 s[2] = {}; \
    __builtin_amdgcn_s_setprio(1); \
    _Pragma("unroll") \
    for (int ni = 0; ni < 2; ++ni) \
      _Pragma("unroll") \
      for (int ks = 0; ks < 4; ++ks) { \
        bf16x8 kf = swzread2(Ks[BUF], l31, ni * 8 + ks * 2 + h5); \
        s[ni] = __builtin_amdgcn_mfma_f32_32x32x16_bf16(kf, qf[ks], s[ni], 0, 0, 0); \
      } \
    __builtin_amdgcn_s_setprio(0); \
    float E[2][16]; \
    _Pragma("unroll") \
    for (int ni = 0; ni < 2; ++ni) \
      _Pragma("unroll") \
      for (int r = 0; r < 16; ++r) { \
        float e = vexp2(s[ni][r]); \
        E[ni][r] = e; \
        dv[r & 3] += e; \
      } \
    bf16x8 pa[4]; \
    _Pragma("unroll") \
    for (int ks = 0; ks < 4; ++ks) { \
      const int ni = ks >> 1, base = (ks & 1) * 8; \
      unsigned A0 = pack2(E[ni][base + 0], E[ni][base + 1]); \
      unsigned A1 = pack2(E[ni][base + 2], E[ni][base + 3]); \
      unsigned B0 = pack2(E[ni][base + 4], E[ni][base + 5]); \
      unsigned B1 = pack2(E[ni][base + 6], E[ni][base + 7]); \
      uint2v r0v = __builtin_amdgcn_permlane32_swap(A0, B0, false, false); \
      uint2v r1v = __builtin_amdgcn_permlane32_swap(A1, B1, false, false); \
      uint4v wv = {r0v[0], r1v[0], r0v[1], r1v[1]}; \
      pa[ks] = __builtin_bit_cast(bf16x8, wv); \
    } \
    __builtin_amdgcn_s_setprio(1); \
    _Pragma("unroll") \
    for (int ks = 0; ks < 4; ++ks) \
      _Pragma("unroll") \
      for (int di = 0; di < 2; ++di) { \
        bf16x8 vf = swzread2(Vts[BUF], l31, di * 8 + ks * 2 + h5); \
        o_acc[di] = __builtin_amdgcn_mfma_f32_32x32x16_bf16(pa[ks], vf, o_acc[di], 0, 0, 0); \
      } \
    __builtin_amdgcn_s_setprio(0); \
    __syncthreads(); \
  } while (0)

  STAGE(0, kvb);
  __syncthreads();

  const int NT = SEQ / 128;            // 32 tiles of 64 kv
  for (int tt = 0; tt < NT; tt += 2) {
    TILE(0, true,           kvb + (tt + 1) * 64);   // tt+1 <= NT-1 always
    TILE(1, (tt + 2) < NT,  kvb + (tt + 2) * 64);
  }

  // denominator: merge 4 chains, cross-half add, plain store per q.
  float den = (dv[0] + dv[1]) + (dv[2] + dv[3]);
  den += __shfl_xor(den, 32);
  if (lane < 32) lsum_part[(size_t)half * 16 * SEQ + (size_t)bh * SEQ + q0 + l31] = den;
  // partial-O: PLAIN bf16 stores (each element owned by exactly one block).
  // PV D: col = lane&31 = d-in-block, row q = (r&3)+8*(r>>2)+4*h5.
  __bf16* op = o_part + (size_t)half * MTOT * DIMC;
  #pragma unroll
  for (int di = 0; di < 2; ++di)
    #pragma unroll
    for (int r = 0; r < 16; ++r) {
      int q = q0 + (r & 3) + 8 * (r >> 2) + 4 * h5;
      op[(size_t)(b * SEQ + q) * DIMC + h * HDIM + di * 32 + l31] = (__bf16)o_acc[di][r];
    }
}

// ---------------- combine: o_ws = (o0+o1) / (l0+l1), bf16 ----------------
__global__ __launch_bounds__(256) void combine_o(const __bf16* __restrict__ o_part,
                                                 const float* __restrict__ lsum_part,
                                                 __bf16* __restrict__ o_ws) {
  int i = blockIdx.x * 256 + threadIdx.x;
  int flat = i * 8;
  int m = flat >> 8, c = flat & 255;
  int h = c >> 6;
  int b = m >> 12, p = m & 4095;
  size_t bhp = (size_t)(b * NHEADS + h) * SEQ + p;
  float inv = 1.f / (lsum_part[bhp] + lsum_part[(size_t)16 * SEQ + bhp]);
  bf16x8 a = *reinterpret_cast<const bf16x8*>(o_part + flat);
  bf16x8 bb = *reinterpret_cast<const bf16x8*>(o_part + (size_t)MTOT * DIMC + flat);
  bf16x8 o;
  #pragma unroll
  for (int j = 0; j < 8; ++j)
    o[j] = (__bf16)(((float)a[j] + (float)bb[j]) * inv);
  *reinterpret_cast<bf16x8*>(o_ws + flat) = o;
}

// ---------------- launch ----------------

extern "C" void kernel_launch(void* const* d_in, const int* in_sizes, int n_in,
                              void* d_out, int out_size, void* d_ws, size_t ws_size,
                              hipStream_t stream) {
  const float* x  = (const float*)d_in[0];
  const float* Wq = (const float*)d_in[1];
  const float* bq = (const float*)d_in[2];
  const float* Wk = (const float*)d_in[3];
  const float* bk = (const float*)d_in[4];
  const float* Wv = (const float*)d_in[5];
  const float* bv = (const float*)d_in[6];
  const float* Wo = (const float*)d_in[7];
  const float* bo = (const float*)d_in[8];
  float* out = (float*)d_out;

  const size_t NE = (size_t)MTOT * DIMC;  // 4,194,304 elements
  char* w = (char*)d_ws;
  __bf16* q_ws   = (__bf16*)w; w += NE * 2;
  __bf16* k_ws   = (__bf16*)w; w += NE * 2;
  __bf16* vt_ws  = (__bf16*)w; w += NE * 2;
  __bf16* wqkvt  = (__bf16*)w; w += (size_t)768 * 256 * 2;
  __bf16* wot    = (__bf16*)w; w += (size_t)256 * 256 * 2;
  float*  biasq  = (float*)w;  w += 768 * 4;
  float*  lsum_p = (float*)w;  w += (size_t)2 * 16 * SEQ * 4;  // 512 KB, plain stores
  __bf16* o_part = (__bf16*)w; w += 2 * NE * 2;                // 16 MB bf16 partials
  // aliases: xb lives in o_part's first half (dead before attn writes o_part);
  // o_ws reuses q_ws (dead after attn prologue; combine runs after attn).
  __bf16* xb   = o_part;
  __bf16* o_ws = q_ws;
  // total ws used: ~41.2 MB; NO memset needed (all buffers fully written).

  cvt_x_kernel<<<MTOT * DIMC / 1024, 256, 0, stream>>>(x, xb);
  prep_w<<<1027, 256, 0, stream>>>(Wq, Wk, Wv, Wo, bq, bk, bv, wqkvt, wot, biasq);
  gemm_bt<0><<<dim3(6, 128), 256, 0, stream>>>(xb, wqkvt, biasq, q_ws, k_ws, vt_ws, nullptr);
  attn_kernel<<<1024, 256, 0, stream>>>(q_ws, k_ws, vt_ws, o_part, lsum_p);
  combine_o<<<NE / 2048, 256, 0, stream>>>(o_part, lsum_p, o_ws);
  gemm_bt<1><<<dim3(2, 128), 256, 0, stream>>>(o_ws, wot, bo, nullptr, nullptr, nullptr, out);
}

// Round 17
// 128.599 us; speedup vs baseline: 1.1480x; 1.1480x over previous
//
#include <hip/hip_runtime.h>
#include <hip/hip_bf16.h>

// MHSA: B=4, P=4096, C=256, H=4, D=64. fp32 in/out, bf16 MFMA internally.
#define DIMC 256
#define NHEADS 4
#define HDIM 64
#define BATCH 4
#define SEQ 4096
#define MTOT (BATCH*SEQ)   // 16384
#define SCALE_LOG2E 0.18033688011112042f  // 0.125 * log2(e); softmax done in exp2 domain

typedef __attribute__((ext_vector_type(8))) __bf16 bf16x8;
typedef __attribute__((ext_vector_type(4))) __bf16 bf16x4;
typedef __attribute__((ext_vector_type(2))) __bf16 bf16x2;
typedef __attribute__((ext_vector_type(4))) float f32x4;
typedef __attribute__((ext_vector_type(16))) float f32x16;
typedef __attribute__((ext_vector_type(2))) unsigned uint2v;
typedef __attribute__((ext_vector_type(4))) unsigned uint4v;

__device__ inline void gll16(const void* g, void* l) {
  // async global->LDS, 16B per lane. LDS dest must be wave-uniform base + lane*16.
  __builtin_amdgcn_global_load_lds((const __attribute__((address_space(1))) unsigned int*)g,
                                   (__attribute__((address_space(3))) unsigned int*)l, 16, 0, 0);
}

// Single v_exp_f32 via the compiler intrinsic (R5 lesson: never raw asm TRANS ops).
__device__ inline float vexp2(float x) { return __builtin_amdgcn_exp2f(x); }

// Pack two f32 -> one u32 of 2 bf16 (RNE). Plain casts (NOT inline asm).
__device__ inline unsigned pack2(float lo, float hi) {
  bf16x2 p; p[0] = (__bf16)lo; p[1] = (__bf16)hi;
  return __builtin_bit_cast(unsigned, p);
}

// Swizzled read from a 64-bf16-row (128B) LDS tile, GEMM variant: chunk' = c16 ^ (row&7).
// Conflict-free for 16-consecutive-row read groups (verified R1: 6.5e7 -> 0).
__device__ inline bf16x8 swzread(const __bf16* base, int row, int c16) {
  return *reinterpret_cast<const bf16x8*>(
      reinterpret_cast<const char*>(base) + row * 128 + ((c16 ^ (row & 7)) << 4));
}

// R16 attn variant: chunk' = c16 ^ ((row>>2)&7). Slot analysis: slot = (8r +
// c^f(r)) mod 32; with f=(r>>2)&7, f is a bijection over each {g+4t} subset ->
// 32 consecutive rows hit 32 DISTINCT bank slots (0-way; R14's f=r&7 gave only
// 2 xor values per subset -> 4-way, the 8.4e6 counts). Staging keeps R14's
// proven-coalesced within-row octet permutation (R15 lesson: 256B-row staging
// pattern quadrupled HBM FETCH — avoided entirely here).
__device__ inline bf16x8 swzreadA(const __bf16* base, int row, int c16) {
  return *reinterpret_cast<const bf16x8*>(
      reinterpret_cast<const char*>(base) + row * 128 + ((c16 ^ ((row >> 2) & 7)) << 4));
}

// ---------------- prep kernels ----------------

__global__ __launch_bounds__(256) void cvt_x_kernel(const float* __restrict__ x, __bf16* __restrict__ xb) {
  int i = (blockIdx.x * 256 + threadIdx.x) * 4;
  float4 v = *reinterpret_cast<const float4*>(x + i);
  bf16x4 o;
  o[0] = (__bf16)v.x; o[1] = (__bf16)v.y; o[2] = (__bf16)v.z; o[3] = (__bf16)v.w;
  *reinterpret_cast<bf16x4*>(xb + i) = o;
}

// Builds Wqkv^T [768][256] (Wq scaled by 0.125*log2e), Wo^T [256][256], and
// (rows 1024..1026) the scaled/merged qkv bias.
__global__ __launch_bounds__(256) void prep_w(const float* __restrict__ Wq, const float* __restrict__ Wk,
                                              const float* __restrict__ Wv, const float* __restrict__ Wo,
                                              const float* __restrict__ bq, const float* __restrict__ bk,
                                              const float* __restrict__ bv,
                                              __bf16* __restrict__ wqkvt, __bf16* __restrict__ wot,
                                              float* __restrict__ biasq) {
  int row = blockIdx.x;        // 0..1026
  int k = threadIdx.x;         // 0..255
  if (row < 768) {
    const float* src; float scale = 1.f; int n = row & 255;
    if (row < 256)      { src = Wq; scale = SCALE_LOG2E; }
    else if (row < 512) { src = Wk; }
    else                { src = Wv; }
    wqkvt[row * 256 + k] = (__bf16)(src[k * 256 + n] * scale);
  } else if (row < 1024) {
    int n = row - 768;
    wot[n * 256 + k] = (__bf16)(Wo[k * 256 + n]);
  } else {
    int i = (row - 1024) * 256 + k;   // 0..767
    biasq[i] = (i < 256) ? bq[i] * SCALE_LOG2E : (i < 512 ? bk[i - 256] : bv[i - 512]);
  }
}

// ---------------- GEMM: C[m][n] = sum_k A[m][k]*Bt[n][k] + bias[n] ----------------
// 128x128 tile, BK=64, 4 waves (2x2 of 64x64), mfma 16x16x32 bf16. T2-swizzled LDS.
// Pure gll16 staging for BOTH operands (R12 lesson: fp32 reg-staging of A cost
// ~16 µs — async global_load_lds is worth more than fusing the cvt).
// MODE 0: scatter q/k into [bh][p][d] and V directly transposed into vt [bh][d][p].
// MODE 1: fp32 out [m][256].
template<int MODE>
__global__ __launch_bounds__(256) void gemm_bt(const __bf16* __restrict__ A, const __bf16* __restrict__ Bt,
                                               const float* __restrict__ bias,
                                               __bf16* __restrict__ q_ws, __bf16* __restrict__ k_ws,
                                               __bf16* __restrict__ vt_ws, float* __restrict__ fout) {
  __shared__ __align__(16) __bf16 As[128 * 64];
  __shared__ __align__(16) __bf16 Bs[128 * 64];
  const int tid = threadIdx.x;
  const int lane = tid & 63, wave = tid >> 6;
  const int wr = wave >> 1, wc = wave & 1;
  const int r16 = lane & 15, g4 = lane >> 4;
  const int m0 = blockIdx.y * 128, n0 = blockIdx.x * 128;
  f32x4 acc[4][4] = {};
  for (int k0 = 0; k0 < DIMC; k0 += 64) {
    #pragma unroll
    for (int it = 0; it < 4; ++it) {
      int e = it * 256 + tid;           // 16B chunk id
      int r = e >> 3, c = e & 7;
      int cs = c ^ (r & 7);             // pre-swizzled source column (rule #21)
      gll16(A  + (size_t)(m0 + r) * DIMC + k0 + cs * 8, As + e * 8);
      gll16(Bt + (size_t)(n0 + r) * DIMC + k0 + cs * 8, Bs + e * 8);
    }
    __syncthreads();
    #pragma unroll
    for (int kk = 0; kk < 2; ++kk) {
      bf16x8 af[4], bfr[4];
      #pragma unroll
      for (int mi = 0; mi < 4; ++mi)
        af[mi] = swzread(As, wr * 64 + mi * 16 + r16, kk * 4 + g4);
      #pragma unroll
      for (int ni = 0; ni < 4; ++ni)
        bfr[ni] = swzread(Bs, wc * 64 + ni * 16 + r16, kk * 4 + g4);
      #pragma unroll
      for (int mi = 0; mi < 4; ++mi)
        #pragma unroll
        for (int ni = 0; ni < 4; ++ni)
          acc[mi][ni] = __builtin_amdgcn_mfma_f32_16x16x32_bf16(af[mi], bfr[ni], acc[mi][ni], 0, 0, 0);
    }
    __syncthreads();
  }
  // Epilogue. C/D layout: col = lane&15, row = (lane>>4)*4 + reg.
  #pragma unroll
  for (int mi = 0; mi < 4; ++mi)
    #pragma unroll
    for (int ni = 0; ni < 4; ++ni)
      #pragma unroll
      for (int r = 0; r < 4; ++r) {
        int m = m0 + wr * 64 + mi * 16 + g4 * 4 + r;
        int n = n0 + wc * 64 + ni * 16 + r16;
        float v = acc[mi][ni][r] + bias[n];
        if (MODE == 0) {
          int b = m >> 12, p = m & 4095;
          int sect = n >> 8, nc = n & 255;
          int h = nc >> 6, d = nc & 63;
          __bf16 hv = (__bf16)v;
          size_t bhb = (size_t)(b * NHEADS + h);
          if (sect == 0)      q_ws[(bhb * SEQ + p) * HDIM + d] = hv;
          else if (sect == 1) k_ws[(bhb * SEQ + p) * HDIM + d] = hv;
          else                vt_ws[(bhb * HDIM + d) * SEQ + p] = hv;  // direct V^T
        } else {
          fout[(size_t)m * DIMC + n] = v;
        }
      }
}

// ---------------- flash attention (split-KV x2, NO atomics) ----------------
// R14 structure kept (32x32x16 core, dv[4] denominator chains, compile-time
// double-buffer unroll, bf16 partial-O plain stores + combine after).
// R16: attn LDS swizzle f(r) = (r>>2)&7 (was r&7) — 32-row ds_read_b128
// groups now hit 32 distinct bank slots (0-way; was 4-way, 8.4e6 counts).
// Staging keeps R14's within-row octet permutation (coalescing class proven
// at 14.4MB FETCH; R15's 256B-row staging pattern hit 68MB and +28µs).
//   S^T = K Q^T: D col=lane&31=q, row kv=(r&3)+8*(r>>2)+4*(lane>>5)+32*ni [m74/m101].
//   p32swap semantics (R7-validated): d0={a.lo32,b.lo32}, d1={a.hi32,b.hi32}.
__global__ __launch_bounds__(256, 4) void attn_kernel(const __bf16* __restrict__ q_ws, const __bf16* __restrict__ k_ws,
                                                      const __bf16* __restrict__ vt_ws,
                                                      __bf16* __restrict__ o_part, float* __restrict__ lsum_part) {
  __shared__ __align__(16) __bf16 Ks[2][64 * 64];   // [kv][d], swizzled (f = (r>>2)&7)
  __shared__ __align__(16) __bf16 Vts[2][64 * 64];  // [d][kv], swizzled (f = (r>>2)&7)
  const int tid = threadIdx.x;
  const int lane = tid & 63;
  const int l31 = lane & 31, h5 = lane >> 5;
  // XCD-bijective swizzle over 1024 blocks: 128 consecutive wgs (2 heads) per XCD.
  int bid = blockIdx.x;
  int wg = (bid & 7) * 128 + (bid >> 3);
  int bh = wg >> 6, rrw = wg & 63;
  int qb = rrw >> 1, half = rrw & 1;
  int b = bh >> 2, h = bh & 3;
  const __bf16* Qp  = q_ws  + (size_t)bh * SEQ * HDIM;
  const __bf16* Kp  = k_ws  + (size_t)bh * SEQ * HDIM;
  const __bf16* Vtp = vt_ws + (size_t)bh * HDIM * SEQ;
  const int q0 = qb * 128 + (tid >> 6) * 32;
  const int kvb = half * (SEQ / 2);
  // Q B-frag: col=lane&31=q, k = ks*16 + h5*8 + j
  bf16x8 qf[4];
  #pragma unroll
  for (int ks = 0; ks < 4; ++ks)
    qf[ks] = *reinterpret_cast<const bf16x8*>(Qp + (size_t)(q0 + l31) * HDIM + ks * 16 + h5 * 8);
  f32x16 o_acc[2] = {};
  f32x4 dv = {};                      // 4 independent denominator chains (R14)

  // staging: 256 threads x 2 chunks x (16B K + 16B Vt); source octet permuted
  // WITHIN the row by f(sr) = (sr>>2)&7. Note ((sr+32)>>2)&7 == (sr>>2)&7, so
  // one base serves both gll16 rows (sr, sr+32) — same as R14's structure.
  const int sr = tid >> 3;
  const int scs = (tid & 7) ^ ((sr >> 2) & 7);
  const __bf16* kSrc = Kp  + (size_t)sr * HDIM + scs * 8;
  const __bf16* vSrc = Vtp + (size_t)sr * SEQ  + scs * 8;

  #define STAGE(buf, kv0) do { \
      gll16(kSrc + (size_t)(kv0) * HDIM,        &Ks[buf][tid * 8]); \
      gll16(kSrc + (size_t)((kv0) + 32) * HDIM, &Ks[buf][(tid + 256) * 8]); \
      gll16(vSrc + (kv0),                       &Vts[buf][tid * 8]); \
      gll16(vSrc + 32 * SEQ + (kv0),            &Vts[buf][(tid + 256) * 8]); \
    } while (0)

  // One KV tile with COMPILE-TIME buffer index BUF; optionally stages
  // the opposite buffer for tile (kv0_next) before compute.
  #define TILE(BUF, DO_STAGE, kv0_next) do { \
    if (DO_STAGE) STAGE(BUF ^ 1, kv0_next); \
    f32x16 s[2] = {}; \
    __builtin_amdgcn_s_setprio(1); \
    _Pragma("unroll") \
    for (int ni = 0; ni < 2; ++ni) \
      _Pragma("unroll") \
      for (int ks = 0; ks < 4; ++ks) { \
        bf16x8 kf = swzreadA(Ks[BUF], ni * 32 + l31, ks * 2 + h5); \
        s[ni] = __builtin_amdgcn_mfma_f32_32x32x16_bf16(kf, qf[ks], s[ni], 0, 0, 0); \
      } \
    __builtin_amdgcn_s_setprio(0); \
    float E[2][16]; \
    _Pragma("unroll") \
    for (int ni = 0; ni < 2; ++ni) \
      _Pragma("unroll") \
      for (int r = 0; r < 16; ++r) { \
        float e = vexp2(s[ni][r]); \
        E[ni][r] = e; \
        dv[r & 3] += e; \
      } \
    bf16x8 pa[4]; \
    _Pragma("unroll") \
    for (int ks = 0; ks < 4; ++ks) { \
      const int ni = ks >> 1, base = (ks & 1) * 8; \
      unsigned A0 = pack2(E[ni][base + 0], E[ni][base + 1]); \
      unsigned A1 = pack2(E[ni][base + 2], E[ni][base + 3]); \
      unsigned B0 = pack2(E[ni][base + 4], E[ni][base + 5]); \
      unsigned B1 = pack2(E[ni][base + 6], E[ni][base + 7]); \
      uint2v r0v = __builtin_amdgcn_permlane32_swap(A0, B0, false, false); \
      uint2v r1v = __builtin_amdgcn_permlane32_swap(A1, B1, false, false); \
      uint4v wv = {r0v[0], r1v[0], r0v[1], r1v[1]}; \
      pa[ks] = __builtin_bit_cast(bf16x8, wv); \
    } \
    __builtin_amdgcn_s_setprio(1); \
    _Pragma("unroll") \
    for (int ks = 0; ks < 4; ++ks) \
      _Pragma("unroll") \
      for (int di = 0; di < 2; ++di) { \
        bf16x8 vf = swzreadA(Vts[BUF], di * 32 + l31, ks * 2 + h5); \
        o_acc[di] = __builtin_amdgcn_mfma_f32_32x32x16_bf16(pa[ks], vf, o_acc[di], 0, 0, 0); \
      } \
    __builtin_amdgcn_s_setprio(0); \
    __syncthreads(); \
  } while (0)

  STAGE(0, kvb);
  __syncthreads();

  const int NT = SEQ / 128;            // 32 tiles of 64 kv
  for (int tt = 0; tt < NT; tt += 2) {
    TILE(0, true,           kvb + (tt + 1) * 64);   // tt+1 <= NT-1 always
    TILE(1, (tt + 2) < NT,  kvb + (tt + 2) * 64);
  }

  // denominator: merge 4 chains, cross-half add, plain store per q.
  float den = (dv[0] + dv[1]) + (dv[2] + dv[3]);
  den += __shfl_xor(den, 32);
  if (lane < 32) lsum_part[(size_t)half * 16 * SEQ + (size_t)bh * SEQ + q0 + l31] = den;
  // partial-O: PLAIN bf16 stores (each element owned by exactly one block).
  // PV D: col = lane&31 = d-in-block, row q = (r&3)+8*(r>>2)+4*h5.
  __bf16* op = o_part + (size_t)half * MTOT * DIMC;
  #pragma unroll
  for (int di = 0; di < 2; ++di)
    #pragma unroll
    for (int r = 0; r < 16; ++r) {
      int q = q0 + (r & 3) + 8 * (r >> 2) + 4 * h5;
      op[(size_t)(b * SEQ + q) * DIMC + h * HDIM + di * 32 + l31] = (__bf16)o_acc[di][r];
    }
}

// ---------------- combine: o_ws = (o0+o1) / (l0+l1), bf16 ----------------
__global__ __launch_bounds__(256) void combine_o(const __bf16* __restrict__ o_part,
                                                 const float* __restrict__ lsum_part,
                                                 __bf16* __restrict__ o_ws) {
  int i = blockIdx.x * 256 + threadIdx.x;
  int flat = i * 8;
  int m = flat >> 8, c = flat & 255;
  int h = c >> 6;
  int b = m >> 12, p = m & 4095;
  size_t bhp = (size_t)(b * NHEADS + h) * SEQ + p;
  float inv = 1.f / (lsum_part[bhp] + lsum_part[(size_t)16 * SEQ + bhp]);
  bf16x8 a = *reinterpret_cast<const bf16x8*>(o_part + flat);
  bf16x8 bb = *reinterpret_cast<const bf16x8*>(o_part + (size_t)MTOT * DIMC + flat);
  bf16x8 o;
  #pragma unroll
  for (int j = 0; j < 8; ++j)
    o[j] = (__bf16)(((float)a[j] + (float)bb[j]) * inv);
  *reinterpret_cast<bf16x8*>(o_ws + flat) = o;
}

// ---------------- launch ----------------

extern "C" void kernel_launch(void* const* d_in, const int* in_sizes, int n_in,
                              void* d_out, int out_size, void* d_ws, size_t ws_size,
                              hipStream_t stream) {
  const float* x  = (const float*)d_in[0];
  const float* Wq = (const float*)d_in[1];
  const float* bq = (const float*)d_in[2];
  const float* Wk = (const float*)d_in[3];
  const float* bk = (const float*)d_in[4];
  const float* Wv = (const float*)d_in[5];
  const float* bv = (const float*)d_in[6];
  const float* Wo = (const float*)d_in[7];
  const float* bo = (const float*)d_in[8];
  float* out = (float*)d_out;

  const size_t NE = (size_t)MTOT * DIMC;  // 4,194,304 elements
  char* w = (char*)d_ws;
  __bf16* q_ws   = (__bf16*)w; w += NE * 2;
  __bf16* k_ws   = (__bf16*)w; w += NE * 2;
  __bf16* vt_ws  = (__bf16*)w; w += NE * 2;
  __bf16* wqkvt  = (__bf16*)w; w += (size_t)768 * 256 * 2;
  __bf16* wot    = (__bf16*)w; w += (size_t)256 * 256 * 2;
  float*  biasq  = (float*)w;  w += 768 * 4;
  float*  lsum_p = (float*)w;  w += (size_t)2 * 16 * SEQ * 4;  // 512 KB, plain stores
  __bf16* o_part = (__bf16*)w; w += 2 * NE * 2;                // 16 MB bf16 partials
  // aliases: xb lives in o_part's first half (dead before attn writes o_part);
  // o_ws reuses q_ws (dead after attn prologue; combine runs after attn).
  __bf16* xb   = o_part;
  __bf16* o_ws = q_ws;
  // total ws used: ~41.2 MB; NO memset needed (all buffers fully written).

  cvt_x_kernel<<<MTOT * DIMC / 1024, 256, 0, stream>>>(x, xb);
  prep_w<<<1027, 256, 0, stream>>>(Wq, Wk, Wv, Wo, bq, bk, bv, wqkvt, wot, biasq);
  gemm_bt<0><<<dim3(6, 128), 256, 0, stream>>>(xb, wqkvt, biasq, q_ws, k_ws, vt_ws, nullptr);
  attn_kernel<<<1024, 256, 0, stream>>>(q_ws, k_ws, vt_ws, o_part, lsum_p);
  combine_o<<<NE / 2048, 256, 0, stream>>>(o_part, lsum_p, o_ws);
  gemm_bt<1><<<dim3(2, 128), 256, 0, stream>>>(o_ws, wot, bo, nullptr, nullptr, nullptr, out);
}